// Round 11
// baseline (324.018 us; speedup 1.0000x reference)
//
#include <hip/hip_runtime.h>

#define HD 128      // hidden / feature dim
#define CLS 10      // num classes
#define BSH 7       // bucket shift: 128 nodes / bucket
#define TS 4096     // edges per scatter tile
#define FCAP 3072   // region capacity per bucket (mean load ~2046)

typedef __attribute__((ext_vector_type(8))) short bf16x8;
typedef __attribute__((ext_vector_type(4))) float floatx4;

// ---- bf16 helpers (manual, RNE) ----
__device__ inline unsigned short f2bf(float f) {
    unsigned u = __float_as_uint(f);
    return (unsigned short)((u + 0x7fffu + ((u >> 16) & 1u)) >> 16);
}
__device__ inline float bflo(unsigned u) { return __uint_as_float(u << 16); }
__device__ inline float bfhi(unsigned u) { return __uint_as_float(u & 0xffff0000u); }

// =============== merged prep: edge bucketing (blocks < NT) + bf16 converts (rest) ===============
// pack: bucket(9b) | src(16b) | local-dst(7b)   [needs N <= 65536]
__global__ __launch_bounds__(512) void k_prep(const int* __restrict__ src, const int* __restrict__ dst,
                                              int* __restrict__ bcnt, unsigned* __restrict__ pairs,
                                              int E, int NB, int NT,
                                              const float* __restrict__ x, unsigned short* __restrict__ h, int total4,
                                              const float* Wr0, const float* Wo0, const float* Wr1, const float* Wo1,
                                              const float* Wr2, const float* Wo2, const float* Wr3, const float* Wo3,
                                              unsigned short* __restrict__ Wcat) {
    int tid = threadIdx.x;
    if ((int)blockIdx.x >= NT) {
        int idx = ((int)blockIdx.x - NT) * 512 + tid;
        if (idx < total4) {
            float4 v = ((const float4*)x)[idx];
            ushort4 o;
            o.x = f2bf(v.x); o.y = f2bf(v.y); o.z = f2bf(v.z); o.w = f2bf(v.w);
            ((ushort4*)h)[idx] = o;
        } else {
            int widx = idx - total4;
            if (widx < 4 * 32768) {
                int l = widx >> 15;
                int i2 = widx & 32767;
                int j = i2 >> 8, k = i2 & 255;
                const float* Wr = (l == 0) ? Wr0 : (l == 1) ? Wr1 : (l == 2) ? Wr2 : Wr3;
                const float* Wo = (l == 0) ? Wo0 : (l == 1) ? Wo1 : (l == 2) ? Wo2 : Wo3;
                float v = (k < 128) ? Wr[j * 128 + k] : Wo[j * 128 + (k - 128)];
                Wcat[(size_t)l * 32768 + i2] = f2bf(v);
            }
        }
        return;
    }
    __shared__ int lh[512];
    __shared__ int lp[512];
    __shared__ int sbase[512];
    __shared__ unsigned lpair[TS];
    int t = blockIdx.x;
    lh[tid] = 0;
    __syncthreads();
    int e0 = t * TS;
    unsigned pk[TS / 512];
    int bk[TS / 512], rk[TS / 512];
    #pragma unroll
    for (int j = 0; j < TS / 512; ++j) {
        int e = e0 + j * 512 + tid;
        if (e < E) {
            int dd = dst[e];
            int b = dd >> BSH;
            pk[j] = ((unsigned)b << 23) | ((unsigned)src[e] << 7) | (unsigned)(dd & 127);
            bk[j] = b;
            rk[j] = atomicAdd(&lh[b], 1);
        } else bk[j] = -1;
    }
    __syncthreads();
    int own = lh[tid];
    lp[tid] = own;
    __syncthreads();
    for (int d = 1; d < 512; d <<= 1) {
        int v = (tid >= d) ? lp[tid - d] : 0;
        __syncthreads();
        lp[tid] += v;
        __syncthreads();
    }
    int excl = lp[tid] - own;
    __syncthreads();
    lh[tid] = excl;
    __syncthreads();
    #pragma unroll
    for (int j = 0; j < TS / 512; ++j) {
        if (bk[j] >= 0) lpair[lh[bk[j]] + rk[j]] = pk[j];
    }
    if (tid < NB) sbase[tid] = own ? atomicAdd(&bcnt[tid], own) : 0;
    __syncthreads();
    int nloc = min(TS, E - e0);
    for (int i = tid; i < nloc; i += 512) {
        unsigned p = lpair[i];
        int b = (int)(p >> 23);
        pairs[(size_t)b * FCAP + sbase[b] + (i - lh[b])] = p;
    }
}

// ---------------- per-bucket exact sort -> eidx (in FCAP regions), deg, start ----------------
__global__ __launch_bounds__(256) void k_fine(const unsigned* __restrict__ pairs, const int* __restrict__ bcnt,
                                              int* __restrict__ eidx, int* __restrict__ deg,
                                              int* __restrict__ start, int N) {
    __shared__ int cnt[128], pref[128];
    __shared__ unsigned spack[FCAP];
    __shared__ unsigned short srk[FCAP];
    int b = blockIdx.x, tid = threadIdx.x;
    int n0 = b << BSH;
    int nn = min(128, N - n0);
    int eb = b * FCAP;
    int ec = min(bcnt[b], FCAP);
    if (tid < 128) cnt[tid] = 0;
    __syncthreads();
    for (int i = tid; i < ec; i += 256) {
        unsigned p = pairs[eb + i];
        int ln = (int)(p & 127u);
        int r = atomicAdd(&cnt[ln], 1);
        spack[i] = p;
        srk[i] = (unsigned short)r;
    }
    __syncthreads();
    if (tid < 128) pref[tid] = cnt[tid];
    __syncthreads();
    for (int d = 1; d < 128; d <<= 1) {
        int v = 0;
        if (tid < 128 && tid >= d) v = pref[tid - d];
        __syncthreads();
        if (tid < 128) pref[tid] += v;
        __syncthreads();
    }
    if (tid < nn) {
        deg[n0 + tid] = cnt[tid];
        start[n0 + tid] = eb + pref[tid] - cnt[tid];
    }
    for (int i = tid; i < ec; i += 256) {
        unsigned p = spack[i];
        int ln = (int)(p & 127u);
        int pos = pref[ln] - cnt[ln] + srk[i];
        eidx[eb + pos] = (int)((p >> 7) & 0xFFFFu);
    }
}

// ---------------- fused layer: per-64-row tile, gather (8 waves) + MFMA ----------------
// Phase 1: wave wv gathers rows wv*8..wv*8+7 into sAgg, processing ROW PAIRS with
//          8 uint4 loads in flight (2 rows x 4 edge slots) to break serial chains.
// Phase 2: hout_tile = relu([sAgg | hin_tile] @ Wcat^T + br); 8 waves in 2x4, 32x32/wave.
__global__ __launch_bounds__(512, 6) void k_layer(const unsigned short* __restrict__ hin,
                                                  const unsigned short* __restrict__ Wcat, const float* __restrict__ br,
                                                  const int* __restrict__ start, const int* __restrict__ deg,
                                                  const int* __restrict__ eidx,
                                                  unsigned short* __restrict__ hout, int N) {
    __shared__ unsigned short sAgg[64][136];   // 17 KB, 272B row stride
    __shared__ unsigned short sB[128][40];     // Wcat slice per step, 10 KB
    __shared__ unsigned short sA[64][40];      // hin slice per step (s>=4), 5 KB
    int tid = threadIdx.x;
    int wv = tid >> 6, lane = tid & 63;
    int nbase = blockIdx.x * 64;
    const uint4* h4 = (const uint4*)hin;

    // ---- phase 1: gather, two rows in flight ----
    int g = lane >> 4, c = lane & 15;
    for (int i = 0; i < 8; i += 2) {
        int na = nbase + wv * 8 + i;
        int nb_ = na + 1;
        int sa = 0, da = 0, sb0 = 0, db = 0;
        if (na < N)  { sa = start[na];  da = deg[na];  }
        if (nb_ < N) { sb0 = start[nb_]; db = deg[nb_]; }
        float a0 = 0.f, a1 = 0.f, a2 = 0.f, a3 = 0.f, a4 = 0.f, a5 = 0.f, a6 = 0.f, a7 = 0.f;
        float b0 = 0.f, b1 = 0.f, b2 = 0.f, b3 = 0.f, b4 = 0.f, b5 = 0.f, b6 = 0.f, b7 = 0.f;
        int ea = 0, eb2 = 0;
        while (ea < da || eb2 < db) {
            int nba = min(64, da - ea);  if (nba < 0) nba = 0;
            int nbb = min(64, db - eb2); if (nbb < 0) nbb = 0;
            int idxa = (lane < nba) ? eidx[sa + ea + lane] : 0;
            int idxb = (lane < nbb) ? eidx[sb0 + eb2 + lane] : 0;
            int jm = max(nba, nbb);
            for (int j = 0; j < jm; j += 16) {
                int e0 = j + g, e1 = j + 4 + g, e2 = j + 8 + g, e3 = j + 12 + g;
                int ia0 = __shfl(idxa, e0 & 63);
                int ia1 = __shfl(idxa, e1 & 63);
                int ia2 = __shfl(idxa, e2 & 63);
                int ia3 = __shfl(idxa, e3 & 63);
                int ib0 = __shfl(idxb, e0 & 63);
                int ib1 = __shfl(idxb, e1 & 63);
                int ib2 = __shfl(idxb, e2 & 63);
                int ib3 = __shfl(idxb, e3 & 63);
                uint4 u0 = make_uint4(0u,0u,0u,0u), u1 = u0, u2 = u0, u3 = u0;
                uint4 v0 = u0, v1 = u0, v2 = u0, v3 = u0;
                if (e0 < nba) u0 = h4[(size_t)ia0 * 16 + c];
                if (e1 < nba) u1 = h4[(size_t)ia1 * 16 + c];
                if (e2 < nba) u2 = h4[(size_t)ia2 * 16 + c];
                if (e3 < nba) u3 = h4[(size_t)ia3 * 16 + c];
                if (e0 < nbb) v0 = h4[(size_t)ib0 * 16 + c];
                if (e1 < nbb) v1 = h4[(size_t)ib1 * 16 + c];
                if (e2 < nbb) v2 = h4[(size_t)ib2 * 16 + c];
                if (e3 < nbb) v3 = h4[(size_t)ib3 * 16 + c];
                a0 += bflo(u0.x) + bflo(u1.x) + bflo(u2.x) + bflo(u3.x);
                a1 += bfhi(u0.x) + bfhi(u1.x) + bfhi(u2.x) + bfhi(u3.x);
                a2 += bflo(u0.y) + bflo(u1.y) + bflo(u2.y) + bflo(u3.y);
                a3 += bfhi(u0.y) + bfhi(u1.y) + bfhi(u2.y) + bfhi(u3.y);
                a4 += bflo(u0.z) + bflo(u1.z) + bflo(u2.z) + bflo(u3.z);
                a5 += bfhi(u0.z) + bfhi(u1.z) + bfhi(u2.z) + bfhi(u3.z);
                a6 += bflo(u0.w) + bflo(u1.w) + bflo(u2.w) + bflo(u3.w);
                a7 += bfhi(u0.w) + bfhi(u1.w) + bfhi(u2.w) + bfhi(u3.w);
                b0 += bflo(v0.x) + bflo(v1.x) + bflo(v2.x) + bflo(v3.x);
                b1 += bfhi(v0.x) + bfhi(v1.x) + bfhi(v2.x) + bfhi(v3.x);
                b2 += bflo(v0.y) + bflo(v1.y) + bflo(v2.y) + bflo(v3.y);
                b3 += bfhi(v0.y) + bfhi(v1.y) + bfhi(v2.y) + bfhi(v3.y);
                b4 += bflo(v0.z) + bflo(v1.z) + bflo(v2.z) + bflo(v3.z);
                b5 += bfhi(v0.z) + bfhi(v1.z) + bfhi(v2.z) + bfhi(v3.z);
                b6 += bflo(v0.w) + bflo(v1.w) + bflo(v2.w) + bflo(v3.w);
                b7 += bfhi(v0.w) + bfhi(v1.w) + bfhi(v2.w) + bfhi(v3.w);
            }
            ea += nba; eb2 += nbb;
        }
        a0 += __shfl_down(a0, 32); a1 += __shfl_down(a1, 32);
        a2 += __shfl_down(a2, 32); a3 += __shfl_down(a3, 32);
        a4 += __shfl_down(a4, 32); a5 += __shfl_down(a5, 32);
        a6 += __shfl_down(a6, 32); a7 += __shfl_down(a7, 32);
        b0 += __shfl_down(b0, 32); b1 += __shfl_down(b1, 32);
        b2 += __shfl_down(b2, 32); b3 += __shfl_down(b3, 32);
        b4 += __shfl_down(b4, 32); b5 += __shfl_down(b5, 32);
        b6 += __shfl_down(b6, 32); b7 += __shfl_down(b7, 32);
        a0 += __shfl_down(a0, 16); a1 += __shfl_down(a1, 16);
        a2 += __shfl_down(a2, 16); a3 += __shfl_down(a3, 16);
        a4 += __shfl_down(a4, 16); a5 += __shfl_down(a5, 16);
        a6 += __shfl_down(a6, 16); a7 += __shfl_down(a7, 16);
        b0 += __shfl_down(b0, 16); b1 += __shfl_down(b1, 16);
        b2 += __shfl_down(b2, 16); b3 += __shfl_down(b3, 16);
        b4 += __shfl_down(b4, 16); b5 += __shfl_down(b5, 16);
        b6 += __shfl_down(b6, 16); b7 += __shfl_down(b7, 16);
        if (g == 0) {
            uint4 oa, ob;
            oa.x = (unsigned)f2bf(a0) | ((unsigned)f2bf(a1) << 16);
            oa.y = (unsigned)f2bf(a2) | ((unsigned)f2bf(a3) << 16);
            oa.z = (unsigned)f2bf(a4) | ((unsigned)f2bf(a5) << 16);
            oa.w = (unsigned)f2bf(a6) | ((unsigned)f2bf(a7) << 16);
            ob.x = (unsigned)f2bf(b0) | ((unsigned)f2bf(b1) << 16);
            ob.y = (unsigned)f2bf(b2) | ((unsigned)f2bf(b3) << 16);
            ob.z = (unsigned)f2bf(b4) | ((unsigned)f2bf(b5) << 16);
            ob.w = (unsigned)f2bf(b6) | ((unsigned)f2bf(b7) << 16);
            *(uint4*)&sAgg[wv * 8 + i][c * 8]     = oa;
            *(uint4*)&sAgg[wv * 8 + i + 1][c * 8] = ob;
        }
    }

    // ---- phase 2: MFMA k-loop; wave tile 32x32 (2 row-groups x 4 col-groups) ----
    int wr2 = wv >> 2, wc2 = wv & 3;
    int m0 = wr2 * 32, n0c = wc2 * 32;
    int lm = lane & 15, quad = lane >> 4;
    int bcol = tid >> 2, bks = (tid & 3) * 8;   // sB staging: 1 uint4/thread
    int arow = tid >> 3, aks = (tid & 7) * 4;   // sA staging: 1 uint2/thread

    floatx4 acc[2][2];
    #pragma unroll
    for (int mt = 0; mt < 2; ++mt)
        #pragma unroll
        for (int nt = 0; nt < 2; ++nt)
            acc[mt][nt] = {0.f, 0.f, 0.f, 0.f};

    for (int s = 0; s < 8; ++s) {
        const unsigned short* gb = Wcat + (size_t)bcol * 256 + s * 32 + bks;
        *(uint4*)&sB[bcol][bks] = *(const uint4*)gb;
        if (s >= 4) {
            int an = nbase + arow;
            uint2 hv = make_uint2(0u, 0u);
            if (an < N) hv = *(const uint2*)(hin + (size_t)an * HD + (s - 4) * 32 + aks);
            *(uint2*)&sA[arow][aks] = hv;
        }
        __syncthreads();
        bf16x8 af[2], bfr[2];
        if (s < 4) {
            #pragma unroll
            for (int mt = 0; mt < 2; ++mt)
                af[mt] = *(const bf16x8*)&sAgg[m0 + mt * 16 + lm][s * 32 + quad * 8];
        } else {
            #pragma unroll
            for (int mt = 0; mt < 2; ++mt)
                af[mt] = *(const bf16x8*)&sA[m0 + mt * 16 + lm][quad * 8];
        }
        #pragma unroll
        for (int nt = 0; nt < 2; ++nt) bfr[nt] = *(const bf16x8*)&sB[n0c + nt * 16 + lm][quad * 8];
        #pragma unroll
        for (int mt = 0; mt < 2; ++mt)
            #pragma unroll
            for (int nt = 0; nt < 2; ++nt)
                acc[mt][nt] = __builtin_amdgcn_mfma_f32_16x16x32_bf16(af[mt], bfr[nt], acc[mt][nt], 0, 0, 0);
        __syncthreads();
    }

    // ---- epilogue: bias + relu + bf16 store ----
    #pragma unroll
    for (int nt = 0; nt < 2; ++nt) {
        int col = n0c + nt * 16 + lm;
        float bias = br[col];
        #pragma unroll
        for (int mt = 0; mt < 2; ++mt) {
            int row0 = nbase + m0 + mt * 16 + quad * 4;
            #pragma unroll
            for (int reg = 0; reg < 4; ++reg) {
                int rr = row0 + reg;
                if (rr < N) {
                    float v = fmaxf(acc[mt][nt][reg] + bias, 0.f);
                    hout[(size_t)rr * HD + col] = f2bf(v);
                }
            }
        }
    }
}

// ---------------- pooling + final linear fused: one block per graph ----------------
__device__ inline int lbound(const int* __restrict__ a, int n, int v) {
    int lo = 0, hi = n;
    while (lo < hi) { int m = (lo + hi) >> 1; if (a[m] < v) lo = m + 1; else hi = m; }
    return lo;
}

__global__ __launch_bounds__(256) void k_poolfinal(const unsigned short* __restrict__ h, const int* __restrict__ batch,
                                                   const float* __restrict__ lw, const float* __restrict__ lb,
                                                   float* __restrict__ out, int N) {
    __shared__ float red[16][128];
    __shared__ float semb[128];
    int g = blockIdx.x, tid = threadIdx.x;
    int lo = lbound(batch, N, g);
    int hi = lbound(batch, N, g + 1);
    int slot = tid >> 4, c = tid & 15;
    const uint4* h4 = (const uint4*)h;
    float a0 = 0.f, a1 = 0.f, a2 = 0.f, a3 = 0.f, a4 = 0.f, a5 = 0.f, a6 = 0.f, a7 = 0.f;
    for (int r = lo + slot; r < hi; r += 16) {
        uint4 u = h4[(size_t)r * 16 + c];
        a0 += bflo(u.x); a1 += bfhi(u.x);
        a2 += bflo(u.y); a3 += bfhi(u.y);
        a4 += bflo(u.z); a5 += bfhi(u.z);
        a6 += bflo(u.w); a7 += bfhi(u.w);
    }
    red[slot][c * 8 + 0] = a0; red[slot][c * 8 + 1] = a1;
    red[slot][c * 8 + 2] = a2; red[slot][c * 8 + 3] = a3;
    red[slot][c * 8 + 4] = a4; red[slot][c * 8 + 5] = a5;
    red[slot][c * 8 + 6] = a6; red[slot][c * 8 + 7] = a7;
    __syncthreads();
    if (tid < 128) {
        float s = 0.f;
        #pragma unroll
        for (int k = 0; k < 16; ++k) s += red[k][tid];
        float cc = fmaxf((float)(hi - lo), 1.0f);
        semb[tid] = s / cc;
    }
    __syncthreads();
    if (tid < CLS) {
        const float* w = lw + tid * HD;
        float s = 0.f;
        #pragma unroll
        for (int k = 0; k < HD; ++k) s += semb[k] * w[k];
        out[g * CLS + tid] = s + lb[tid];
    }
}

extern "C" void kernel_launch(void* const* d_in, const int* in_sizes, int n_in,
                              void* d_out, int out_size, void* d_ws, size_t ws_size,
                              hipStream_t stream) {
    const float* x     = (const float*)d_in[0];
    const int*   ei    = (const int*)d_in[1];
    const int*   batch = (const int*)d_in[2];
    const float* Wr[4]  = {(const float*)d_in[3], (const float*)d_in[6], (const float*)d_in[9],  (const float*)d_in[12]};
    const float* brl[4] = {(const float*)d_in[4], (const float*)d_in[7], (const float*)d_in[10], (const float*)d_in[13]};
    const float* Wo[4]  = {(const float*)d_in[5], (const float*)d_in[8], (const float*)d_in[11], (const float*)d_in[14]};
    const float* lw = (const float*)d_in[15];
    const float* lb = (const float*)d_in[16];
    float* out = (float*)d_out;

    int N = in_sizes[0] / HD;
    int E = in_sizes[1] / 2;
    int G = out_size / CLS;
    int NB = (N + 127) >> 7;            // buckets (<=512 for N<=65536)
    int Np = NB * 128;
    int NT = (E + TS - 1) / TS;         // scatter tiles
    const int* src = ei;
    const int* dst = ei + E;

    // ---- workspace layout (zero-needed regions first) ----
    char* ws = (char*)d_ws;
    size_t off_b = 0;
    auto alloc = [&](size_t bytes) -> char* {
        char* p = ws + off_b;
        off_b += (bytes + 255) & ~(size_t)255;
        return p;
    };
    int* bcnt = (int*)alloc((size_t)NB * 4);           // zeroed
    size_t zero_bytes = off_b;
    unsigned* pairs = (unsigned*)alloc((size_t)NB * FCAP * 4);
    int*   eidx   = (int*)alloc((size_t)NB * FCAP * 4);
    int*   deg    = (int*)alloc((size_t)N * 4);
    int*   startp = (int*)alloc((size_t)N * 4);
    unsigned short* hbuf0 = (unsigned short*)alloc((size_t)Np * HD * 2);
    unsigned short* hbuf1 = (unsigned short*)alloc((size_t)Np * HD * 2);
    unsigned short* Wcat  = (unsigned short*)alloc((size_t)4 * 128 * 256 * 2);

    hipMemsetAsync(d_ws, 0, zero_bytes, stream);

    // ---- prep: scatter (blocks < NT) + converts (rest) in one launch ----
    int total4 = N * HD / 4;
    int cvt_items = total4 + 4 * 32768;
    int cvt_blocks = (cvt_items + 511) / 512;
    k_prep<<<NT + cvt_blocks, 512, 0, stream>>>(src, dst, bcnt, pairs, E, NB, NT,
                                                x, hbuf0, total4,
                                                Wr[0], Wo[0], Wr[1], Wo[1], Wr[2], Wo[2], Wr[3], Wo[3], Wcat);
    k_fine<<<NB, 256, 0, stream>>>(pairs, bcnt, eidx, deg, startp, N);

    // ---- 4 fused GraphConv layers (gather + MFMA per 64-row tile) ----
    unsigned short* hcur = hbuf0;
    unsigned short* hnxt = hbuf1;
    for (int l = 0; l < 4; ++l) {
        k_layer<<<Np / 64, 512, 0, stream>>>(hcur, Wcat + (size_t)l * 32768, brl[l],
                                             startp, deg, eidx, hnxt, N);
        unsigned short* t = hcur; hcur = hnxt; hnxt = t;
    }

    // ---- pooling + final linear ----
    k_poolfinal<<<G, 256, 0, stream>>>(hcur, batch, lw, lb, out, N);
}

// Round 12
// 288.811 us; speedup vs baseline: 1.1219x; 1.1219x over previous
//
#include <hip/hip_runtime.h>

#define HD 128      // hidden / feature dim
#define CLS 10      // num classes
#define BSH 7       // bucket shift: 128 nodes / bucket
#define TS 4096     // edges per scatter tile
#define FCAP 3072   // region capacity per bucket (mean load ~2046)

typedef __attribute__((ext_vector_type(8))) short bf16x8;
typedef __attribute__((ext_vector_type(4))) float floatx4;

// ---- bf16 helpers (manual, RNE) ----
__device__ inline unsigned short f2bf(float f) {
    unsigned u = __float_as_uint(f);
    return (unsigned short)((u + 0x7fffu + ((u >> 16) & 1u)) >> 16);
}
__device__ inline float bflo(unsigned u) { return __uint_as_float(u << 16); }
__device__ inline float bfhi(unsigned u) { return __uint_as_float(u & 0xffff0000u); }

// =============== merged prep: edge bucketing (blocks < NT) + bf16 converts (rest) ===============
// pack: bucket(9b) | src(16b) | local-dst(7b)   [needs N <= 65536]
__global__ __launch_bounds__(512) void k_prep(const int* __restrict__ src, const int* __restrict__ dst,
                                              int* __restrict__ bcnt, unsigned* __restrict__ pairs,
                                              int E, int NB, int NT,
                                              const float* __restrict__ x, unsigned short* __restrict__ h, int total4,
                                              const float* Wr0, const float* Wo0, const float* Wr1, const float* Wo1,
                                              const float* Wr2, const float* Wo2, const float* Wr3, const float* Wo3,
                                              unsigned short* __restrict__ Wcat) {
    int tid = threadIdx.x;
    if ((int)blockIdx.x >= NT) {
        int idx = ((int)blockIdx.x - NT) * 512 + tid;
        if (idx < total4) {
            float4 v = ((const float4*)x)[idx];
            ushort4 o;
            o.x = f2bf(v.x); o.y = f2bf(v.y); o.z = f2bf(v.z); o.w = f2bf(v.w);
            ((ushort4*)h)[idx] = o;
        } else {
            int widx = idx - total4;
            if (widx < 4 * 32768) {
                int l = widx >> 15;
                int i2 = widx & 32767;
                int j = i2 >> 8, k = i2 & 255;
                const float* Wr = (l == 0) ? Wr0 : (l == 1) ? Wr1 : (l == 2) ? Wr2 : Wr3;
                const float* Wo = (l == 0) ? Wo0 : (l == 1) ? Wo1 : (l == 2) ? Wo2 : Wo3;
                float v = (k < 128) ? Wr[j * 128 + k] : Wo[j * 128 + (k - 128)];
                Wcat[(size_t)l * 32768 + i2] = f2bf(v);
            }
        }
        return;
    }
    __shared__ int lh[512];
    __shared__ int lp[512];
    __shared__ int sbase[512];
    __shared__ unsigned lpair[TS];
    int t = blockIdx.x;
    lh[tid] = 0;
    __syncthreads();
    int e0 = t * TS;
    unsigned pk[TS / 512];
    int bk[TS / 512], rk[TS / 512];
    #pragma unroll
    for (int j = 0; j < TS / 512; ++j) {
        int e = e0 + j * 512 + tid;
        if (e < E) {
            int dd = dst[e];
            int b = dd >> BSH;
            pk[j] = ((unsigned)b << 23) | ((unsigned)src[e] << 7) | (unsigned)(dd & 127);
            bk[j] = b;
            rk[j] = atomicAdd(&lh[b], 1);
        } else bk[j] = -1;
    }
    __syncthreads();
    int own = lh[tid];
    lp[tid] = own;
    __syncthreads();
    for (int d = 1; d < 512; d <<= 1) {
        int v = (tid >= d) ? lp[tid - d] : 0;
        __syncthreads();
        lp[tid] += v;
        __syncthreads();
    }
    int excl = lp[tid] - own;
    __syncthreads();
    lh[tid] = excl;
    __syncthreads();
    #pragma unroll
    for (int j = 0; j < TS / 512; ++j) {
        if (bk[j] >= 0) lpair[lh[bk[j]] + rk[j]] = pk[j];
    }
    if (tid < NB) sbase[tid] = own ? atomicAdd(&bcnt[tid], own) : 0;
    __syncthreads();
    int nloc = min(TS, E - e0);
    for (int i = tid; i < nloc; i += 512) {
        unsigned p = lpair[i];
        int b = (int)(p >> 23);
        pairs[(size_t)b * FCAP + sbase[b] + (i - lh[b])] = p;
    }
}

// ---------------- per-bucket exact sort -> eidx (in FCAP regions), deg, start ----------------
__global__ __launch_bounds__(256) void k_fine(const unsigned* __restrict__ pairs, const int* __restrict__ bcnt,
                                              int* __restrict__ eidx, int* __restrict__ deg,
                                              int* __restrict__ start, int N) {
    __shared__ int cnt[128], pref[128];
    __shared__ unsigned spack[FCAP];
    __shared__ unsigned short srk[FCAP];
    int b = blockIdx.x, tid = threadIdx.x;
    int n0 = b << BSH;
    int nn = min(128, N - n0);
    int eb = b * FCAP;
    int ec = min(bcnt[b], FCAP);
    if (tid < 128) cnt[tid] = 0;
    __syncthreads();
    for (int i = tid; i < ec; i += 256) {
        unsigned p = pairs[eb + i];
        int ln = (int)(p & 127u);
        int r = atomicAdd(&cnt[ln], 1);
        spack[i] = p;
        srk[i] = (unsigned short)r;
    }
    __syncthreads();
    if (tid < 128) pref[tid] = cnt[tid];
    __syncthreads();
    for (int d = 1; d < 128; d <<= 1) {
        int v = 0;
        if (tid < 128 && tid >= d) v = pref[tid - d];
        __syncthreads();
        if (tid < 128) pref[tid] += v;
        __syncthreads();
    }
    if (tid < nn) {
        deg[n0 + tid] = cnt[tid];
        start[n0 + tid] = eb + pref[tid] - cnt[tid];
    }
    for (int i = tid; i < ec; i += 256) {
        unsigned p = spack[i];
        int ln = (int)(p & 127u);
        int pos = pref[ln] - cnt[ln] + srk[i];
        eidx[eb + pos] = (int)((p >> 7) & 0xFFFFu);
    }
}

// ---------------- fused layer: per-64-row tile, gather (8 waves) + MFMA ----------------
// Phase 1: wave wv gathers rows wv*8..wv*8+7 into sAgg (R5 gather shape: lane=g*16+c,
//          16 edges/iter, register accumulate, no LDS atomics).
// Phase 2: hout_tile = relu([sAgg | hin_tile] @ Wcat^T + br); 8 waves in 2x4, 32x32/wave.
__global__ __launch_bounds__(512, 6) void k_layer(const unsigned short* __restrict__ hin,
                                                  const unsigned short* __restrict__ Wcat, const float* __restrict__ br,
                                                  const int* __restrict__ start, const int* __restrict__ deg,
                                                  const int* __restrict__ eidx,
                                                  unsigned short* __restrict__ hout, int N) {
    __shared__ unsigned short sAgg[64][136];   // 17 KB, 272B row stride (2-way banks on rw)
    __shared__ unsigned short sB[128][40];     // Wcat slice per step, 10 KB
    __shared__ unsigned short sA[64][40];      // hin slice per step (s>=4), 5 KB
    int tid = threadIdx.x;
    int wv = tid >> 6, lane = tid & 63;
    int nbase = blockIdx.x * 64;
    const uint4* h4 = (const uint4*)hin;

    // ---- phase 1: gather 8 rows per wave ----
    int g = lane >> 4, c = lane & 15;
    for (int i = 0; i < 8; ++i) {
        int rloc = wv * 8 + i;
        int n = nbase + rloc;
        int s0 = 0, d = 0;
        if (n < N) { s0 = start[n]; d = deg[n]; }
        float a0 = 0.f, a1 = 0.f, a2 = 0.f, a3 = 0.f, a4 = 0.f, a5 = 0.f, a6 = 0.f, a7 = 0.f;
        int e = 0;
        while (e < d) {
            int nb = min(64, d - e);
            int myidx = (lane < nb) ? eidx[s0 + e + lane] : 0;
            for (int j = 0; j < nb; j += 16) {
                int e0 = j + g, e1 = j + 4 + g, e2 = j + 8 + g, e3 = j + 12 + g;
                int i0 = __shfl(myidx, e0 & 63);
                int i1 = __shfl(myidx, e1 & 63);
                int i2 = __shfl(myidx, e2 & 63);
                int i3 = __shfl(myidx, e3 & 63);
                uint4 u0 = make_uint4(0u,0u,0u,0u), u1 = u0, u2 = u0, u3 = u0;
                if (e0 < nb) u0 = h4[(size_t)i0 * 16 + c];
                if (e1 < nb) u1 = h4[(size_t)i1 * 16 + c];
                if (e2 < nb) u2 = h4[(size_t)i2 * 16 + c];
                if (e3 < nb) u3 = h4[(size_t)i3 * 16 + c];
                a0 += bflo(u0.x) + bflo(u1.x) + bflo(u2.x) + bflo(u3.x);
                a1 += bfhi(u0.x) + bfhi(u1.x) + bfhi(u2.x) + bfhi(u3.x);
                a2 += bflo(u0.y) + bflo(u1.y) + bflo(u2.y) + bflo(u3.y);
                a3 += bfhi(u0.y) + bfhi(u1.y) + bfhi(u2.y) + bfhi(u3.y);
                a4 += bflo(u0.z) + bflo(u1.z) + bflo(u2.z) + bflo(u3.z);
                a5 += bfhi(u0.z) + bfhi(u1.z) + bfhi(u2.z) + bfhi(u3.z);
                a6 += bflo(u0.w) + bflo(u1.w) + bflo(u2.w) + bflo(u3.w);
                a7 += bfhi(u0.w) + bfhi(u1.w) + bfhi(u2.w) + bfhi(u3.w);
            }
            e += nb;
        }
        a0 += __shfl_down(a0, 32); a1 += __shfl_down(a1, 32);
        a2 += __shfl_down(a2, 32); a3 += __shfl_down(a3, 32);
        a4 += __shfl_down(a4, 32); a5 += __shfl_down(a5, 32);
        a6 += __shfl_down(a6, 32); a7 += __shfl_down(a7, 32);
        a0 += __shfl_down(a0, 16); a1 += __shfl_down(a1, 16);
        a2 += __shfl_down(a2, 16); a3 += __shfl_down(a3, 16);
        a4 += __shfl_down(a4, 16); a5 += __shfl_down(a5, 16);
        a6 += __shfl_down(a6, 16); a7 += __shfl_down(a7, 16);
        if (g == 0) {
            uint4 o;
            o.x = (unsigned)f2bf(a0) | ((unsigned)f2bf(a1) << 16);
            o.y = (unsigned)f2bf(a2) | ((unsigned)f2bf(a3) << 16);
            o.z = (unsigned)f2bf(a4) | ((unsigned)f2bf(a5) << 16);
            o.w = (unsigned)f2bf(a6) | ((unsigned)f2bf(a7) << 16);
            *(uint4*)&sAgg[rloc][c * 8] = o;
        }
    }
    // (no barrier needed here: step 0's staging barrier below covers sAgg writes)

    // ---- phase 2: MFMA k-loop; wave tile 32x32 (2 row-groups x 4 col-groups) ----
    int wr2 = wv >> 2, wc2 = wv & 3;
    int m0 = wr2 * 32, n0c = wc2 * 32;
    int lm = lane & 15, quad = lane >> 4;
    int bcol = tid >> 2, bks = (tid & 3) * 8;   // sB staging: 1 uint4/thread
    int arow = tid >> 3, aks = (tid & 7) * 4;   // sA staging: 1 uint2/thread

    floatx4 acc[2][2];
    #pragma unroll
    for (int mt = 0; mt < 2; ++mt)
        #pragma unroll
        for (int nt = 0; nt < 2; ++nt)
            acc[mt][nt] = {0.f, 0.f, 0.f, 0.f};

    for (int s = 0; s < 8; ++s) {
        // stage B (128 cols x 32 k)
        const unsigned short* gb = Wcat + (size_t)bcol * 256 + s * 32 + bks;
        *(uint4*)&sB[bcol][bks] = *(const uint4*)gb;
        // stage A-hin for s>=4 (64 rows x 32 k)
        if (s >= 4) {
            int an = nbase + arow;
            uint2 hv = make_uint2(0u, 0u);
            if (an < N) hv = *(const uint2*)(hin + (size_t)an * HD + (s - 4) * 32 + aks);
            *(uint2*)&sA[arow][aks] = hv;
        }
        __syncthreads();
        bf16x8 af[2], bfr[2];
        if (s < 4) {
            #pragma unroll
            for (int mt = 0; mt < 2; ++mt)
                af[mt] = *(const bf16x8*)&sAgg[m0 + mt * 16 + lm][s * 32 + quad * 8];
        } else {
            #pragma unroll
            for (int mt = 0; mt < 2; ++mt)
                af[mt] = *(const bf16x8*)&sA[m0 + mt * 16 + lm][quad * 8];
        }
        #pragma unroll
        for (int nt = 0; nt < 2; ++nt) bfr[nt] = *(const bf16x8*)&sB[n0c + nt * 16 + lm][quad * 8];
        #pragma unroll
        for (int mt = 0; mt < 2; ++mt)
            #pragma unroll
            for (int nt = 0; nt < 2; ++nt)
                acc[mt][nt] = __builtin_amdgcn_mfma_f32_16x16x32_bf16(af[mt], bfr[nt], acc[mt][nt], 0, 0, 0);
        __syncthreads();
    }

    // ---- epilogue: bias + relu + bf16 store ----
    #pragma unroll
    for (int nt = 0; nt < 2; ++nt) {
        int col = n0c + nt * 16 + lm;
        float bias = br[col];
        #pragma unroll
        for (int mt = 0; mt < 2; ++mt) {
            int row0 = nbase + m0 + mt * 16 + quad * 4;
            #pragma unroll
            for (int reg = 0; reg < 4; ++reg) {
                int rr = row0 + reg;
                if (rr < N) {
                    float v = fmaxf(acc[mt][nt][reg] + bias, 0.f);
                    hout[(size_t)rr * HD + col] = f2bf(v);
                }
            }
        }
    }
}

// ---------------- pooling + final linear fused: one block per graph ----------------
__device__ inline int lbound(const int* __restrict__ a, int n, int v) {
    int lo = 0, hi = n;
    while (lo < hi) { int m = (lo + hi) >> 1; if (a[m] < v) lo = m + 1; else hi = m; }
    return lo;
}

__global__ __launch_bounds__(256) void k_poolfinal(const unsigned short* __restrict__ h, const int* __restrict__ batch,
                                                   const float* __restrict__ lw, const float* __restrict__ lb,
                                                   float* __restrict__ out, int N) {
    __shared__ float red[16][128];
    __shared__ float semb[128];
    int g = blockIdx.x, tid = threadIdx.x;
    int lo = lbound(batch, N, g);
    int hi = lbound(batch, N, g + 1);
    int slot = tid >> 4, c = tid & 15;
    const uint4* h4 = (const uint4*)h;
    float a0 = 0.f, a1 = 0.f, a2 = 0.f, a3 = 0.f, a4 = 0.f, a5 = 0.f, a6 = 0.f, a7 = 0.f;
    for (int r = lo + slot; r < hi; r += 16) {
        uint4 u = h4[(size_t)r * 16 + c];
        a0 += bflo(u.x); a1 += bfhi(u.x);
        a2 += bflo(u.y); a3 += bfhi(u.y);
        a4 += bflo(u.z); a5 += bfhi(u.z);
        a6 += bflo(u.w); a7 += bfhi(u.w);
    }
    red[slot][c * 8 + 0] = a0; red[slot][c * 8 + 1] = a1;
    red[slot][c * 8 + 2] = a2; red[slot][c * 8 + 3] = a3;
    red[slot][c * 8 + 4] = a4; red[slot][c * 8 + 5] = a5;
    red[slot][c * 8 + 6] = a6; red[slot][c * 8 + 7] = a7;
    __syncthreads();
    if (tid < 128) {
        float s = 0.f;
        #pragma unroll
        for (int k = 0; k < 16; ++k) s += red[k][tid];
        float cc = fmaxf((float)(hi - lo), 1.0f);
        semb[tid] = s / cc;
    }
    __syncthreads();
    if (tid < CLS) {
        const float* w = lw + tid * HD;
        float s = 0.f;
        #pragma unroll
        for (int k = 0; k < HD; ++k) s += semb[k] * w[k];
        out[g * CLS + tid] = s + lb[tid];
    }
}

extern "C" void kernel_launch(void* const* d_in, const int* in_sizes, int n_in,
                              void* d_out, int out_size, void* d_ws, size_t ws_size,
                              hipStream_t stream) {
    const float* x     = (const float*)d_in[0];
    const int*   ei    = (const int*)d_in[1];
    const int*   batch = (const int*)d_in[2];
    const float* Wr[4]  = {(const float*)d_in[3], (const float*)d_in[6], (const float*)d_in[9],  (const float*)d_in[12]};
    const float* brl[4] = {(const float*)d_in[4], (const float*)d_in[7], (const float*)d_in[10], (const float*)d_in[13]};
    const float* Wo[4]  = {(const float*)d_in[5], (const float*)d_in[8], (const float*)d_in[11], (const float*)d_in[14]};
    const float* lw = (const float*)d_in[15];
    const float* lb = (const float*)d_in[16];
    float* out = (float*)d_out;

    int N = in_sizes[0] / HD;
    int E = in_sizes[1] / 2;
    int G = out_size / CLS;
    int NB = (N + 127) >> 7;            // buckets (<=512 for N<=65536)
    int Np = NB * 128;
    int NT = (E + TS - 1) / TS;         // scatter tiles
    const int* src = ei;
    const int* dst = ei + E;

    // ---- workspace layout (zero-needed regions first) ----
    char* ws = (char*)d_ws;
    size_t off_b = 0;
    auto alloc = [&](size_t bytes) -> char* {
        char* p = ws + off_b;
        off_b += (bytes + 255) & ~(size_t)255;
        return p;
    };
    int* bcnt = (int*)alloc((size_t)NB * 4);           // zeroed
    size_t zero_bytes = off_b;
    unsigned* pairs = (unsigned*)alloc((size_t)NB * FCAP * 4);
    int*   eidx   = (int*)alloc((size_t)NB * FCAP * 4);
    int*   deg    = (int*)alloc((size_t)N * 4);
    int*   startp = (int*)alloc((size_t)N * 4);
    unsigned short* hbuf0 = (unsigned short*)alloc((size_t)Np * HD * 2);
    unsigned short* hbuf1 = (unsigned short*)alloc((size_t)Np * HD * 2);
    unsigned short* Wcat  = (unsigned short*)alloc((size_t)4 * 128 * 256 * 2);

    hipMemsetAsync(d_ws, 0, zero_bytes, stream);

    // ---- prep: scatter (blocks < NT) + converts (rest) in one launch ----
    int total4 = N * HD / 4;
    int cvt_items = total4 + 4 * 32768;
    int cvt_blocks = (cvt_items + 511) / 512;
    k_prep<<<NT + cvt_blocks, 512, 0, stream>>>(src, dst, bcnt, pairs, E, NB, NT,
                                                x, hbuf0, total4,
                                                Wr[0], Wo[0], Wr[1], Wo[1], Wr[2], Wo[2], Wr[3], Wo[3], Wcat);
    k_fine<<<NB, 256, 0, stream>>>(pairs, bcnt, eidx, deg, startp, N);

    // ---- 4 fused GraphConv layers (gather + MFMA per 64-row tile) ----
    unsigned short* hcur = hbuf0;
    unsigned short* hnxt = hbuf1;
    for (int l = 0; l < 4; ++l) {
        k_layer<<<Np / 64, 512, 0, stream>>>(hcur, Wcat + (size_t)l * 32768, brl[l],
                                             startp, deg, eidx, hnxt, N);
        unsigned short* t = hcur; hcur = hnxt; hnxt = t;
    }

    // ---- pooling + final linear ----
    k_poolfinal<<<G, 256, 0, stream>>>(hcur, batch, lw, lb, out, N);
}